// Round 1
// 142.164 us; speedup vs baseline: 1.0011x; 1.0011x over previous
//
#include <hip/hip_runtime.h>

#define EXTENT 7
#define CHANNELS 256
#define NPTS (EXTENT * EXTENT)  // 49

typedef float v4f __attribute__((ext_vector_type(4)));

// Grid = 4 * n_boxes. blockIdx = q*n_boxes + box. 256 threads:
// (tid & 63) -> 4 channels via v4f (64 lanes x 16B = full 1KB channel row,
// coalesced); sub = q*4 + (tid>>6) in [0,16) -> 3 grid points per wave
// (+ point 48 on sub==0, wave-uniform branch).
//
// R3 change: explicit 3-stage software pipeline (addresses -> ALL 12 loads
// -> blends/stores). Previous version had VGPR_Count=20, proving the
// compiler serialized to one point's 4 taps in flight (s_waitcnt vmcnt(0)
// per point) -> latency-bound at 3.4 TB/s. Staging into named registers
// triples per-wave MLP; target is the ~6.3 TB/s BW ceiling (~23 us floor:
// 93 MB fetch ~= p2+p3 footprint, 50 MB write = output, both near-minimal).
__global__ __launch_bounds__(256) void roi_align_pyramid_kernel(
    const float* __restrict__ metadata,
    const float* __restrict__ boxes,
    const float* __restrict__ p2,
    const float* __restrict__ p3,
    const float* __restrict__ p4,
    const float* __restrict__ p5,
    float* __restrict__ out,
    int n_boxes)
{
    const int box = blockIdx.x % n_boxes;
    const int q   = blockIdx.x / n_boxes;      // 0..3
    const int tid = threadIdx.x;
    const int sub = (q << 2) | (tid >> 6);     // 0..15, uniform per wave
    const int c   = (tid & 63) << 2;           // channel offset

    const float rows = metadata[0];
    const float cols = metadata[1];

    const float x1 = boxes[box * 4 + 0];
    const float y1 = boxes[box * 4 + 1];
    const float x2 = boxes[box * 4 + 2];
    const float y2 = boxes[box * 4 + 3];

    // Level selection — replicate reference fp32 math.
    const float h = y2 - y1;
    const float w = x2 - x1;
    float roi_level = logf(sqrtf(h * w) / sqrtf(rows * cols)) / logf(2.0f);
    roi_level = fminf(5.0f, fmaxf(2.0f, 4.0f + rintf(roi_level)));
    const int lvl = (int)roi_level;  // 2..5

    const float* feat;
    int H;
    if      (lvl == 2) { feat = p2; H = 256; }
    else if (lvl == 3) { feat = p3; H = 128; }
    else if (lvl == 4) { feat = p4; H = 64; }
    else               { feat = p5; H = 32; }
    const int W = H;
    const size_t rowstr = (size_t)W * CHANNELS;

    // Normalized box coords (tf.crop_and_resize convention).
    const float ny1 = y1 / (rows - 1.0f);
    const float ny2 = y2 / (rows - 1.0f);
    const float nx1 = x1 / (cols - 1.0f);
    const float nx2 = x2 / (cols - 1.0f);

    float* outp = out + (size_t)box * NPTS * CHANNELS + c;

    // Stage 0: addresses + weights for a point.
    auto setup = [&](int p, const float*& base,
                     float& w00, float& w01, float& w10, float& w11) {
        const int gy = p / EXTENT;
        const int gx = p - gy * EXTENT;

        const float gyf = (float)gy / (float)(EXTENT - 1);
        const float ysv = (ny1 + (ny2 - ny1) * gyf) * (float)(H - 1);
        float y0f = floorf(ysv);
        y0f = fminf(fmaxf(y0f, 0.0f), (float)(H - 2));
        const int   y0 = (int)y0f;
        const float wy = ysv - y0f;

        const float gxf = (float)gx / (float)(EXTENT - 1);
        const float xsv = (nx1 + (nx2 - nx1) * gxf) * (float)(W - 1);
        float x0f = floorf(xsv);
        x0f = fminf(fmaxf(x0f, 0.0f), (float)(W - 2));
        const int   x0 = (int)x0f;
        const float wx = xsv - x0f;

        base = feat + ((size_t)(y0 * W + x0)) * CHANNELS + c;
        w00 = (1.0f - wy) * (1.0f - wx);
        w01 = (1.0f - wy) * wx;
        w10 = wy * (1.0f - wx);
        w11 = wy * wx;
    };

    const float* base[3];
    float w00[3], w01[3], w10[3], w11[3];
    #pragma unroll
    for (int k = 0; k < 3; ++k)
        setup(sub + 16 * k, base[k], w00[k], w01[k], w10[k], w11[k]);

    // Stage 1: issue ALL loads before any use (static indices -> registers).
    v4f f00[3], f01[3], f10[3], f11[3];
    #pragma unroll
    for (int k = 0; k < 3; ++k) {
        f00[k] = *(const v4f*)(base[k]);
        f01[k] = *(const v4f*)(base[k] + CHANNELS);
        f10[k] = *(const v4f*)(base[k] + rowstr);
        f11[k] = *(const v4f*)(base[k] + rowstr + CHANNELS);
    }

    // Tail point 48 (sub==0 only; sub is wave-uniform so no divergence):
    // issue its loads before the blend phase so they overlap the blends.
    const bool tail = (sub == 0);
    const float* tb = base[0];
    float t00 = 0.f, t01 = 0.f, t10 = 0.f, t11 = 0.f;
    v4f g00 = {}, g01 = {}, g10 = {}, g11 = {};
    if (tail) {
        setup(48, tb, t00, t01, t10, t11);
        g00 = *(const v4f*)(tb);
        g01 = *(const v4f*)(tb + CHANNELS);
        g10 = *(const v4f*)(tb + rowstr);
        g11 = *(const v4f*)(tb + rowstr + CHANNELS);
    }

    // Stage 2: blend + store (write-once data: nontemporal keeps feature
    // lines resident in L2).
    #pragma unroll
    for (int k = 0; k < 3; ++k) {
        v4f r = f00[k] * w00[k] + f01[k] * w01[k]
              + f10[k] * w10[k] + f11[k] * w11[k];
        __builtin_nontemporal_store(r, (v4f*)(outp + (size_t)(sub + 16 * k) * CHANNELS));
    }
    if (tail) {
        v4f r = g00 * t00 + g01 * t01 + g10 * t10 + g11 * t11;
        __builtin_nontemporal_store(r, (v4f*)(outp + (size_t)48 * CHANNELS));
    }
}

extern "C" void kernel_launch(void* const* d_in, const int* in_sizes, int n_in,
                              void* d_out, int out_size, void* d_ws, size_t ws_size,
                              hipStream_t stream) {
    const float* metadata = (const float*)d_in[0];
    const float* boxes    = (const float*)d_in[1];
    const float* p2       = (const float*)d_in[2];
    const float* p3       = (const float*)d_in[3];
    const float* p4       = (const float*)d_in[4];
    const float* p5       = (const float*)d_in[5];
    float* out = (float*)d_out;

    const int n_boxes = in_sizes[1] / 4;  // 1024
    dim3 grid(n_boxes * 4);
    dim3 block(256);
    roi_align_pyramid_kernel<<<grid, block, 0, stream>>>(
        metadata, boxes, p2, p3, p4, p5, out, n_boxes);
}